// Round 4
// baseline (427.727 us; speedup 1.0000x reference)
//
#include <hip/hip_runtime.h>

#define B 8
#define CCH 3
#define HH 512
#define WW 512
#define HW (HH * WW)
#define WIN 21
#define PAD 10
#define TSX 32
#define TSY 32
#define PTY 52                 // TSY + 2*PAD rows staged
#define TROW 60                // tile row stride (dwords): 28r+4c sweeps all 32 banks
#define HSH 53                 // hs rows per column
#define NSLOT 676              // 52 rows x 13 float4 groups
#define NGRP 2                 // batch groups (blocks per output tile)
#define BPG 4                  // batches per group
#define NTILES ((HH / TSY) * (WW / TSX) * CCH)   // 768

// lgkm-only barrier: orders LDS producer/consumer without draining vmcnt,
// so cross-batch global prefetches stay in flight across barriers.
__device__ __forceinline__ void lds_barrier() {
    asm volatile("s_waitcnt lgkmcnt(0)" ::: "memory");
    __builtin_amdgcn_s_barrier();
    asm volatile("" ::: "memory");
}

__global__ __launch_bounds__(256, 4) void nlm_part_kernel(const float* __restrict__ noisy,
                                                          float* __restrict__ out,
                                                          int* __restrict__ cnt) {
    __shared__ float  tile[PTY][TROW];     // 12480 B
    __shared__ float2 hs_t[TSX][HSH];      // 13568 B  -> 26 KB: LDS fits 6 blocks/CU
    __shared__ int    who;

    const int tid = threadIdx.x;
    const int x0 = blockIdx.x * TSX;
    const int y0 = blockIdx.y * TSY;
    const int zz = blockIdx.z;             // 0..5
    const int g  = zz / CCH;               // batch group 0/1
    const int ch = zz - g * CCH;
    const int tileid = (ch * (HH / TSY) + blockIdx.y) * (WW / TSX) + blockIdx.x;

    // ---- precompute staging slots (addresses batch-invariant) ----
    int   rowbase[3], gxs[3];
    float* ldsp[3];
    bool  valid[3], edge[3];
    #pragma unroll
    for (int k = 0; k < 3; ++k) {
        int s = tid + 256 * k;
        valid[k] = (s < NSLOT);
        int ss = valid[k] ? s : 0;
        int r  = ss / 13;
        int c4 = ss - r * 13;
        int gy = y0 + r - PAD;
        gy = (gy < 0) ? -gy : ((gy >= HH) ? (2 * (HH - 1) - gy) : gy);
        int gx = x0 + (c4 << 2) - PAD;
        rowbase[k] = gy * WW;
        gxs[k]     = gx;
        edge[k]    = (gx < 0) || (gx > WW - 4);
        ldsp[k]    = &tile[r][c4 << 2];
    }

    const int b0 = g * BPG;
    const float* src0 = noisy + (size_t)(b0 * CCH + ch) * HW;
    float4 pre[3];
    // prefetch first batch of this group
    #pragma unroll
    for (int k = 0; k < 3; ++k) {
        if (valid[k]) {
            if (!edge[k]) {
                pre[k] = *(const float4*)(src0 + rowbase[k] + gxs[k]);
            } else {
                float tmp[4];
                #pragma unroll
                for (int t = 0; t < 4; ++t) {
                    int gx = gxs[k] + t;
                    gx = (gx < 0) ? -gx : ((gx >= WW) ? (2 * (WW - 1) - gx) : gx);
                    tmp[t] = src0[rowbase[k] + gx];
                }
                pre[k] = make_float4(tmp[0], tmp[1], tmp[2], tmp[3]);
            }
        }
    }

    float num[4] = {0.f, 0.f, 0.f, 0.f};
    float den[4] = {0.f, 0.f, 0.f, 0.f};

    const int tx  = tid & 31;
    const int ty0 = (tid >> 5) << 2;       // 4 consecutive output rows / thread
    const float kE = (-100.0f / 441.0f) * 1.44269504088896f;  // fold 1/h^2/n/ln2

    for (int lb = 0; lb < BPG; ++lb) {
        lds_barrier();                     // Btop: previous V's tile/hs reads done
        #pragma unroll
        for (int k = 0; k < 3; ++k)
            if (valid[k]) *(float4*)ldsp[k] = pre[k];
        lds_barrier();                     // B1: tile visible

        // issue next batch's global loads now; in flight across H+V+Btop
        if (lb < BPG - 1) {
            const float* srcn = noisy + (size_t)((b0 + lb + 1) * CCH + ch) * HW;
            #pragma unroll
            for (int k = 0; k < 3; ++k) {
                if (valid[k]) {
                    if (!edge[k]) {
                        pre[k] = *(const float4*)(srcn + rowbase[k] + gxs[k]);
                    } else {
                        float tmp[4];
                        #pragma unroll
                        for (int t = 0; t < 4; ++t) {
                            int gx = gxs[k] + t;
                            gx = (gx < 0) ? -gx : ((gx >= WW) ? (2 * (WW - 1) - gx) : gx);
                            tmp[t] = srcn[rowbase[k] + gx];
                        }
                        pre[k] = make_float4(tmp[0], tmp[1], tmp[2], tmp[3]);
                    }
                }
            }
        }

        // ---- horizontal box sums: 52 rows x 4 segments of 8 output cols ----
        if (tid < PTY * 4) {
            int r   = tid >> 2;
            int cx0 = (tid & 3) << 3;      // 0,8,16,24
            float v[28];
            #pragma unroll
            for (int q = 0; q < 7; ++q)
                *(float4*)&v[q * 4] = *(const float4*)&tile[r][cx0 + (q << 2)];
            float s1 = 0.f, s2 = 0.f;
            #pragma unroll
            for (int k = 0; k <= 20; ++k) { s1 += v[k]; s2 = fmaf(v[k], v[k], s2); }
            hs_t[cx0][r] = make_float2(s1, s2);
            #pragma unroll
            for (int j = 1; j < 8; ++j) {
                float vo = v[j - 1], vn = v[j + 20];
                s1 += vn - vo;
                s2 += vn * vn - vo * vo;
                hs_t[cx0 + j][r] = make_float2(s1, s2);
            }
        }
        lds_barrier();                     // B2: hs visible

        // ---- vertical sliding sums: 4 output rows per thread ----
        float2 h0 = hs_t[tx][ty0];
        float2 h1 = hs_t[tx][ty0 + 1];
        float2 h2 = hs_t[tx][ty0 + 2];
        float vs1 = h0.x + h1.x + h2.x;
        float vs2 = h0.y + h1.y + h2.y;
        #pragma unroll
        for (int k = 3; k <= 20; ++k) {
            float2 h = hs_t[tx][ty0 + k];
            vs1 += h.x;
            vs2 += h.y;
        }
        {
            float a = tile[ty0 + PAD][tx + PAD];
            float p = tile[ty0][tx];
            float dd = fmaf(a, fmaf(441.f, a, -2.f * vs1), vs2);
            float w = exp2f(dd * kE);
            num[0] += w * p; den[0] += w;
        }
        #pragma unroll
        for (int i = 1; i < 4; ++i) {
            float2 hn = hs_t[tx][ty0 + 20 + i];
            float2 ho = (i == 1) ? h0 : ((i == 2) ? h1 : h2);
            vs1 += hn.x - ho.x;
            vs2 += hn.y - ho.y;
            float a = tile[ty0 + i + PAD][tx + PAD];
            float p = tile[ty0 + i][tx];
            float dd = fmaf(a, fmaf(441.f, a, -2.f * vs1), vs2);
            float w = exp2f(dd * kE);
            num[i] += w * p; den[i] += w;
        }
    }

    // ---- write this group's partials into scratch output slices g*2, g*2+1 ----
    const int y = y0 + ty0;
    const int x = x0 + tx;
    const size_t sliceN = ((size_t)((g * 2 + 0) * CCH + ch)) * HW;
    const size_t sliceD = ((size_t)((g * 2 + 1) * CCH + ch)) * HW;
    #pragma unroll
    for (int i = 0; i < 4; ++i) {
        out[sliceN + (size_t)(y + i) * WW + x] = num[i];
        out[sliceD + (size_t)(y + i) * WW + x] = den[i];
    }
    __threadfence();                        // device-scope: partials visible
    __syncthreads();                        // all threads' stores+fences done
    if (tid == 0) who = atomicAdd(&cnt[tileid], 1);
    __syncthreads();

    if (who == 1) {                         // second arriver combines + finalizes
        __threadfence();                    // acquire side
        const int og = 1 - g;
        const size_t osliceN = ((size_t)((og * 2 + 0) * CCH + ch)) * HW;
        const size_t osliceD = ((size_t)((og * 2 + 1) * CCH + ch)) * HW;
        #pragma unroll
        for (int i = 0; i < 4; ++i) {
            const size_t px = (size_t)(y + i) * WW + x;
            float n2 = out[osliceN + px];
            float d2 = out[osliceD + px];
            float v = (num[i] + n2) / ((den[i] + d2) + 1e-10f);
            v = v < 0.f ? 0.f : (v > 1.f ? 1.f : v);
            #pragma unroll
            for (int bb = 0; bb < B; ++bb)
                out[(size_t)(bb * CCH + ch) * HW + px] = v;
        }
    }
}

extern "C" void kernel_launch(void* const* d_in, const int* in_sizes, int n_in,
                              void* d_out, int out_size, void* d_ws, size_t ws_size,
                              hipStream_t stream) {
    const float* noisy = (const float*)d_in[0];
    float* out = (float*)d_out;
    int* cnt = (int*)d_ws;
    hipMemsetAsync(cnt, 0, NTILES * sizeof(int), stream);
    dim3 grid(WW / TSX, HH / TSY, CCH * NGRP);
    nlm_part_kernel<<<grid, dim3(256), 0, stream>>>(noisy, out, cnt);
}

// Round 5
// 94.289 us; speedup vs baseline: 4.5363x; 4.5363x over previous
//
#include <hip/hip_runtime.h>

#define B 8
#define CCH 3
#define HH 512
#define WW 512
#define HW (HH * WW)
#define WIN 21
#define PAD 10
#define TSX 32
#define TSY 32
#define PTY 52                 // TSY + 2*PAD rows staged
#define TROW 60                // tile row stride (dwords): 28r+4c sweeps all 32 banks
#define HSH 53                 // hs rows per column
#define NSLOT 676              // 52 rows x 13 float4 groups
#define HTASK (PTY * 4)        // 208 horizontal tasks per batch

// lgkm-only barrier: orders LDS producer/consumer without draining vmcnt,
// so cross-pair global prefetches stay in flight across barriers.
__device__ __forceinline__ void lds_barrier() {
    asm volatile("s_waitcnt lgkmcnt(0)" ::: "memory");
    __builtin_amdgcn_s_barrier();
    asm volatile("" ::: "memory");
}

__global__ __launch_bounds__(256, 3) void nlm_fused_kernel(const float* __restrict__ noisy,
                                                           float* __restrict__ out) {
    __shared__ float  tile[2][PTY][TROW];   // 24960 B (batch-pair: two live tiles)
    __shared__ float2 hs_t[2][TSX][HSH];    // 27136 B -> 52096 B total: 3 blocks/CU

    const int tid = threadIdx.x;
    const int x0 = blockIdx.x * TSX;
    const int y0 = blockIdx.y * TSY;
    const int ch = blockIdx.z;

    // ---- precompute staging slots (identical for both batches of a pair) ----
    int   rowbase[3], gxs[3];
    int   ldso[3];
    bool  valid[3], edge[3];
    #pragma unroll
    for (int k = 0; k < 3; ++k) {
        int s = tid + 256 * k;
        valid[k] = (s < NSLOT);
        int ss = valid[k] ? s : 0;
        int r  = ss / 13;
        int c4 = ss - r * 13;
        int gy = y0 + r - PAD;
        gy = (gy < 0) ? -gy : ((gy >= HH) ? (2 * (HH - 1) - gy) : gy);
        int gx = x0 + (c4 << 2) - PAD;
        rowbase[k] = gy * WW;
        gxs[k]     = gx;
        edge[k]    = (gx < 0) || (gx > WW - 4);
        ldso[k]    = r * TROW + (c4 << 2);
    }

    float4 pre[2][3];
    // prefetch pair 0 (batches 0 and 1)
    #pragma unroll
    for (int u = 0; u < 2; ++u) {
        const float* src = noisy + (size_t)(u * CCH + ch) * HW;
        #pragma unroll
        for (int k = 0; k < 3; ++k) {
            if (valid[k]) {
                if (!edge[k]) {
                    pre[u][k] = *(const float4*)(src + rowbase[k] + gxs[k]);
                } else {
                    float tmp[4];
                    #pragma unroll
                    for (int t = 0; t < 4; ++t) {
                        int gx = gxs[k] + t;
                        gx = (gx < 0) ? -gx : ((gx >= WW) ? (2 * (WW - 1) - gx) : gx);
                        tmp[t] = src[rowbase[k] + gx];
                    }
                    pre[u][k] = make_float4(tmp[0], tmp[1], tmp[2], tmp[3]);
                }
            }
        }
    }

    float num[4] = {0.f, 0.f, 0.f, 0.f};
    float den[4] = {0.f, 0.f, 0.f, 0.f};

    const int tx  = tid & 31;
    const int ty0 = (tid >> 5) << 2;       // 4 consecutive output rows / thread
    const float kE = (-100.0f / 441.0f) * 1.44269504088896f;  // fold 1/h^2/n/ln2

    for (int pb = 0; pb < B; pb += 2) {
        lds_barrier();                     // Btop: previous pair's tile/hs reads done
        #pragma unroll
        for (int u = 0; u < 2; ++u)
            #pragma unroll
            for (int k = 0; k < 3; ++k)
                if (valid[k]) *(float4*)(&tile[u][0][0] + ldso[k]) = pre[u][k];
        lds_barrier();                     // B1: both tiles visible

        // issue next pair's 6 global loads; stay in flight across B2/V/Btop
        if (pb < B - 2) {
            #pragma unroll
            for (int u = 0; u < 2; ++u) {
                const float* srcn = noisy + (size_t)((pb + 2 + u) * CCH + ch) * HW;
                #pragma unroll
                for (int k = 0; k < 3; ++k) {
                    if (valid[k]) {
                        if (!edge[k]) {
                            pre[u][k] = *(const float4*)(srcn + rowbase[k] + gxs[k]);
                        } else {
                            float tmp[4];
                            #pragma unroll
                            for (int t = 0; t < 4; ++t) {
                                int gx = gxs[k] + t;
                                gx = (gx < 0) ? -gx : ((gx >= WW) ? (2 * (WW - 1) - gx) : gx);
                                tmp[t] = srcn[rowbase[k] + gx];
                            }
                            pre[u][k] = make_float4(tmp[0], tmp[1], tmp[2], tmp[3]);
                        }
                    }
                }
            }
        }

        // ---- horizontal box sums: 416 tasks over 256 threads (160 do both) ----
        auto hwork = [&](int u, int t) {
            int r   = t >> 2;
            int cx0 = (t & 3) << 3;        // 0,8,16,24
            float v[28];
            #pragma unroll
            for (int q = 0; q < 7; ++q)
                *(float4*)&v[q * 4] = *(const float4*)&tile[u][r][cx0 + (q << 2)];
            float s1 = 0.f, s2 = 0.f;
            #pragma unroll
            for (int k = 0; k <= 20; ++k) { s1 += v[k]; s2 = fmaf(v[k], v[k], s2); }
            hs_t[u][cx0][r] = make_float2(s1, s2);
            #pragma unroll
            for (int j = 1; j < 8; ++j) {
                float vo = v[j - 1], vn = v[j + 20];
                s1 += vn - vo;
                s2 += vn * vn - vo * vo;
                hs_t[u][cx0 + j][r] = make_float2(s1, s2);
            }
        };
        if (tid < HTASK) hwork(0, tid);            // batch pb:   threads 0..207
        if (tid >= 48)   hwork(1, tid - 48);       // batch pb+1: threads 48..255
        lds_barrier();                     // B2: both hs visible

        // ---- vertical sliding sums: two independent chains per thread ----
        const float2* colA = &hs_t[0][tx][0];
        const float2* colB = &hs_t[1][tx][0];
        float2 hA0 = colA[ty0], hA1 = colA[ty0 + 1], hA2 = colA[ty0 + 2];
        float2 hB0 = colB[ty0], hB1 = colB[ty0 + 1], hB2 = colB[ty0 + 2];
        float vs1A = hA0.x + hA1.x + hA2.x, vs2A = hA0.y + hA1.y + hA2.y;
        float vs1B = hB0.x + hB1.x + hB2.x, vs2B = hB0.y + hB1.y + hB2.y;
        #pragma unroll
        for (int k = 3; k <= 20; ++k) {
            float2 hA = colA[ty0 + k];
            float2 hB = colB[ty0 + k];
            vs1A += hA.x; vs2A += hA.y;
            vs1B += hB.x; vs2B += hB.y;
        }
        {
            float aA = tile[0][ty0 + PAD][tx + PAD];
            float pA = tile[0][ty0][tx];
            float aB = tile[1][ty0 + PAD][tx + PAD];
            float pB = tile[1][ty0][tx];
            float ddA = fmaf(aA, fmaf(441.f, aA, -2.f * vs1A), vs2A);
            float ddB = fmaf(aB, fmaf(441.f, aB, -2.f * vs1B), vs2B);
            float wA = exp2f(ddA * kE);
            float wB = exp2f(ddB * kE);
            num[0] += wA * pA; den[0] += wA;       // batch pb first,
            num[0] += wB * pB; den[0] += wB;       // then pb+1: exact r0 order
        }
        #pragma unroll
        for (int i = 1; i < 4; ++i) {
            float2 hnA = colA[ty0 + 20 + i];
            float2 hnB = colB[ty0 + 20 + i];
            float2 hoA = (i == 1) ? hA0 : ((i == 2) ? hA1 : hA2);
            float2 hoB = (i == 1) ? hB0 : ((i == 2) ? hB1 : hB2);
            vs1A += hnA.x - hoA.x; vs2A += hnA.y - hoA.y;
            vs1B += hnB.x - hoB.x; vs2B += hnB.y - hoB.y;
            float aA = tile[0][ty0 + i + PAD][tx + PAD];
            float pA = tile[0][ty0 + i][tx];
            float aB = tile[1][ty0 + i + PAD][tx + PAD];
            float pB = tile[1][ty0 + i][tx];
            float ddA = fmaf(aA, fmaf(441.f, aA, -2.f * vs1A), vs2A);
            float ddB = fmaf(aB, fmaf(441.f, aB, -2.f * vs1B), vs2B);
            float wA = exp2f(ddA * kE);
            float wB = exp2f(ddB * kE);
            num[i] += wA * pA; den[i] += wA;
            num[i] += wB * pB; den[i] += wB;
        }
    }

    // ---- epilogue: identical value for all 8 batch slices ----
    #pragma unroll
    for (int i = 0; i < 4; ++i) {
        int y = y0 + ty0 + i;
        int x = x0 + tx;
        float v = num[i] / (den[i] + 1e-10f);
        v = v < 0.f ? 0.f : (v > 1.f ? 1.f : v);
        #pragma unroll
        for (int bb = 0; bb < B; ++bb)
            out[((size_t)(bb * CCH + ch) * HH + y) * WW + x] = v;
    }
}

extern "C" void kernel_launch(void* const* d_in, const int* in_sizes, int n_in,
                              void* d_out, int out_size, void* d_ws, size_t ws_size,
                              hipStream_t stream) {
    const float* noisy = (const float*)d_in[0];
    float* out = (float*)d_out;
    dim3 grid(WW / TSX, HH / TSY, CCH);
    nlm_fused_kernel<<<grid, dim3(256), 0, stream>>>(noisy, out);
}